// Round 1
// 112.657 us; speedup vs baseline: 1.0373x; 1.0373x over previous
//
#include <hip/hip_runtime.h>

// RandomAttention: B=2, S=2048, NH=8, H=64, NKEYS=64, fp32.
// One wave per (b, q, head). Lane remap: g = lane>>4 (key group),
// c = lane&15 (float4 chunk of the 64-float row). Each 16-lane group
// owns one key row per iteration -> every K/V wave-load covers 4 full
// 256B rows. Scores finish with 4 intra-group DPP shuffles.
//
// R1 changes vs baseline (52us/dispatch):
//  (a) Head-major XCD-aligned mapping: head e = blockIdx.x & 7. Blocks
//      round-robin across the 8 XCDs, so each XCD serves exactly one
//      head; the per-head gather working set (k+v head slices, both
//      batches) is 2 MB and fits in one XCD's 4 MB L2. The random-key
//      re-reads (avg 64x reuse per key row) become L2 hits instead of
//      LLC/HBM fetches.
//  (b) V prefetch: V loads are issued in phase 1 alongside the K loads
//      (same row offset), held in 16 float4 regs. Phase 2 becomes pure
//      VALU - removes the second serialized gather-latency chain.
//  (c) Deferred normalization: accumulate with un-normalized exp
//      weights, scale the final accumulator by 1/sum once.

#define BB 2
#define SS 2048
#define NHH 8
#define HH 64
#define NKEYS 64

__global__ __launch_bounds__(256, 4) void rand_attn_kernel(
    const float* __restrict__ q, const float* __restrict__ k,
    const float* __restrict__ v, const int* __restrict__ idx,
    float* __restrict__ out) {
  const int warp = threadIdx.x >> 6;
  const int lane = threadIdx.x & 63;
  const int g = lane >> 4;   // key group 0..3 (key n == 4*j + g)
  const int c = lane & 15;   // float4 chunk within the 64-float row

  // Head == XCD (blocks dispatch round-robin over 8 XCDs).
  const int e = blockIdx.x & 7;                     // head
  const int bq = ((blockIdx.x >> 3) << 2) + warp;   // b*S + s, 4 per block
  const int b = bq >> 11;                           // S = 2048

  // q chunk for this lane (replicated across the 4 groups), pre-scaled.
  const float* qrow = q + ((size_t)bq * NHH + e) * HH;
  float4 q4 = ((const float4*)qrow)[c];
  q4.x *= 0.125f; q4.y *= 0.125f; q4.z *= 0.125f; q4.w *= 0.125f;

  // Lane n holds idx[bq, n] (coalesced 256B load).
  const int myidx = idx[(size_t)bq * NKEYS + lane];
  const float* kb = k + (size_t)b * (SS * NHH * HH);
  const float* vb = v + (size_t)b * (SS * NHH * HH);

  float sc[16];    // this group's scores (all 16 lanes of a group agree)
  float4 vv[16];   // prefetched V chunks (phase 2 becomes pure VALU)

  // Phase 1: scores + V prefetch. Iteration j: group g handles key 4j+g.
#pragma unroll
  for (int j = 0; j < 16; ++j) {
    const int n = 4 * j + g;
    const int vi = __builtin_amdgcn_ds_bpermute(n << 2, myidx);
    const size_t roff = ((size_t)vi * NHH + e) * HH;
    float4 kv = ((const float4*)(kb + roff))[c];
    vv[j] = ((const float4*)(vb + roff))[c];   // independent; issues early
    float t = kv.x * q4.x + kv.y * q4.y + kv.z * q4.z + kv.w * q4.w;
    t += __shfl_xor(t, 1, 64);   // intra-group (16-lane) reduce: DPP
    t += __shfl_xor(t, 2, 64);
    t += __shfl_xor(t, 4, 64);
    t += __shfl_xor(t, 8, 64);
    sc[j] = t;
  }

  // Softmax over all 64 keys (16 per lane within group + cross-group).
  float m = sc[0];
#pragma unroll
  for (int j = 1; j < 16; ++j) m = fmaxf(m, sc[j]);
  m = fmaxf(m, __shfl_xor(m, 16, 64));
  m = fmaxf(m, __shfl_xor(m, 32, 64));
  float ssum = 0.f;
#pragma unroll
  for (int j = 0; j < 16; ++j) {
    sc[j] = __expf(sc[j] - m);
    ssum += sc[j];
  }
  ssum += __shfl_xor(ssum, 16, 64);
  ssum += __shfl_xor(ssum, 32, 64);
  const float inv = 1.0f / ssum;   // wave-uniform; applied once at the end

  // Phase 2: PV on prefetched registers (no memory ops).
  float4 acc = make_float4(0.f, 0.f, 0.f, 0.f);
#pragma unroll
  for (int j = 0; j < 16; ++j) {
    acc.x += sc[j] * vv[j].x;
    acc.y += sc[j] * vv[j].y;
    acc.z += sc[j] * vv[j].z;
    acc.w += sc[j] * vv[j].w;
  }
  // Cross-group sum (xor 16, 32) -> every lane has the full result.
  acc.x += __shfl_xor(acc.x, 16, 64);
  acc.y += __shfl_xor(acc.y, 16, 64);
  acc.z += __shfl_xor(acc.z, 16, 64);
  acc.w += __shfl_xor(acc.w, 16, 64);
  acc.x += __shfl_xor(acc.x, 32, 64);
  acc.y += __shfl_xor(acc.y, 32, 64);
  acc.z += __shfl_xor(acc.z, 32, 64);
  acc.w += __shfl_xor(acc.w, 32, 64);
  acc.x *= inv; acc.y *= inv; acc.z *= inv; acc.w *= inv;

  if (g == 0) {
    ((float4*)(out + ((size_t)bq * NHH + e) * HH))[c] = acc;
  }
}

extern "C" void kernel_launch(void* const* d_in, const int* in_sizes, int n_in,
                              void* d_out, int out_size, void* d_ws,
                              size_t ws_size, hipStream_t stream) {
  const float* q = (const float*)d_in[0];
  const float* k = (const float*)d_in[1];
  const float* v = (const float*)d_in[2];
  const int* idx = (const int*)d_in[3];
  float* out = (float*)d_out;

  // B*S*NH = 32768 waves; 4 waves per 256-thread block -> 8192 blocks.
  const int n_blocks = (BB * SS * NHH) / 4;
  rand_attn_kernel<<<n_blocks, 256, 0, stream>>>(q, k, v, idx, out);
}

// Round 2
// 111.815 us; speedup vs baseline: 1.0451x; 1.0075x over previous
//
#include <hip/hip_runtime.h>

// RandomAttention: B=2, S=2048, NH=8, H=64, NKEYS=64, fp32.
// One wave per (b, q, head). Lane remap: g = lane>>4 (key group),
// c = lane&15 (float4 chunk of the 64-float row). Each 16-lane group
// owns one key row per iteration -> every K/V wave-load covers 4 full
// 256B rows. Scores finish with 4 intra-group DPP shuffles.
//
// R1 (kept): head-major XCD mapping (e = blockIdx.x & 7) pins each
// head's 2MB gather slice in one XCD's 4MB L2 (FETCH 60.6->16.4 MB).
//
// R2 changes (R1 dur unchanged at ~52us; VGPR stayed 56 => compiler
// SANK the V prefetch back past softmax, recreating the serial
// latency chain):
//  (a) Explicit phase structure with sched_barrier(0) pins:
//      [all 16 offsets] -> [all 16 K loads] || [dot+reduce]
//      -> [all 16 V loads] -> barrier -> [softmax] -> [PV].
//      16 loads in flight per wave; softmax hides the V-gather
//      latency. sched_barrier(0) stops hipcc re-sinking the loads.
//  (b) One shared foff[16] (float4-unit offsets) for K and V - the
//      address VALU chain is computed once.
//  (c) v_rcp_f32 via __builtin_amdgcn_rcpf instead of 1/x div-fixup.

#define BB 2
#define SS 2048
#define NHH 8
#define HH 64
#define NKEYS 64

__global__ __launch_bounds__(256, 4) void rand_attn_kernel(
    const float* __restrict__ q, const float* __restrict__ k,
    const float* __restrict__ v, const int* __restrict__ idx,
    float* __restrict__ out) {
  const int warp = threadIdx.x >> 6;
  const int lane = threadIdx.x & 63;
  const int g = lane >> 4;   // key group 0..3 (key n == 4*j + g)
  const int c = lane & 15;   // float4 chunk within the 64-float row

  // Head == XCD (blocks dispatch round-robin over 8 XCDs).
  const int e = blockIdx.x & 7;                     // head
  const int bq = ((blockIdx.x >> 3) << 2) + warp;   // b*S + s, 4 per block
  const int b = bq >> 11;                           // S = 2048

  // q chunk for this lane (replicated across the 4 groups), pre-scaled.
  const float* qrow = q + ((size_t)bq * NHH + e) * HH;
  float4 q4 = ((const float4*)qrow)[c];
  q4.x *= 0.125f; q4.y *= 0.125f; q4.z *= 0.125f; q4.w *= 0.125f;

  // Lane n holds idx[bq, n] (coalesced 256B load).
  const int myidx = idx[(size_t)bq * NKEYS + lane];
  const float4* kb4 = (const float4*)(k + (size_t)b * (SS * NHH * HH));
  const float4* vb4 = (const float4*)(v + (size_t)b * (SS * NHH * HH));
  const int co = (e << 4) + c;   // within-row float4 offset: e*16 + c

  // Phase 0: all 16 key-row offsets (float4 units). Row base for key
  // index vi is (vi*NHH + e)*HH floats = vi*128 + e*16 float4.
  int foff[16];
#pragma unroll
  for (int j = 0; j < 16; ++j) {
    const int n = 4 * j + g;
    const int vi = __builtin_amdgcn_ds_bpermute(n << 2, myidx);
    foff[j] = (vi << 7) + co;
  }

  // Phase 1a: issue ALL 16 K loads (max MLP), pinned above the dots.
  float4 k4[16];
#pragma unroll
  for (int j = 0; j < 16; ++j) k4[j] = kb4[foff[j]];
  __builtin_amdgcn_sched_barrier(0);

  // Phase 1b: dots + intra-group (16-lane) DPP reduce.
  float sc[16];
#pragma unroll
  for (int j = 0; j < 16; ++j) {
    float t = k4[j].x * q4.x + k4[j].y * q4.y + k4[j].z * q4.z +
              k4[j].w * q4.w;
    t += __shfl_xor(t, 1, 64);
    t += __shfl_xor(t, 2, 64);
    t += __shfl_xor(t, 4, 64);
    t += __shfl_xor(t, 8, 64);
    sc[j] = t;
  }

  // Phase 2a: issue ALL 16 V loads BEFORE softmax; the barrier stops
  // the scheduler from sinking them back below it (R1's failure mode).
  float4 vv[16];
#pragma unroll
  for (int j = 0; j < 16; ++j) vv[j] = vb4[foff[j]];
  __builtin_amdgcn_sched_barrier(0);

  // Phase 2b: softmax over all 64 keys (overlaps V-gather latency).
  float m = sc[0];
#pragma unroll
  for (int j = 1; j < 16; ++j) m = fmaxf(m, sc[j]);
  m = fmaxf(m, __shfl_xor(m, 16, 64));
  m = fmaxf(m, __shfl_xor(m, 32, 64));
  float ssum = 0.f;
#pragma unroll
  for (int j = 0; j < 16; ++j) {
    sc[j] = __expf(sc[j] - m);
    ssum += sc[j];
  }
  ssum += __shfl_xor(ssum, 16, 64);
  ssum += __shfl_xor(ssum, 32, 64);
  const float inv = __builtin_amdgcn_rcpf(ssum);  // wave-uniform

  // Phase 3: PV on prefetched registers (pure VALU).
  float4 acc = make_float4(0.f, 0.f, 0.f, 0.f);
#pragma unroll
  for (int j = 0; j < 16; ++j) {
    acc.x += sc[j] * vv[j].x;
    acc.y += sc[j] * vv[j].y;
    acc.z += sc[j] * vv[j].z;
    acc.w += sc[j] * vv[j].w;
  }
  // Cross-group sum (xor 16, 32) -> every lane has the full result.
  acc.x += __shfl_xor(acc.x, 16, 64);
  acc.y += __shfl_xor(acc.y, 16, 64);
  acc.z += __shfl_xor(acc.z, 16, 64);
  acc.w += __shfl_xor(acc.w, 16, 64);
  acc.x += __shfl_xor(acc.x, 32, 64);
  acc.y += __shfl_xor(acc.y, 32, 64);
  acc.z += __shfl_xor(acc.z, 32, 64);
  acc.w += __shfl_xor(acc.w, 32, 64);
  acc.x *= inv; acc.y *= inv; acc.z *= inv; acc.w *= inv;

  if (g == 0) {
    ((float4*)(out + ((size_t)bq * NHH + e) * HH))[c] = acc;
  }
}

extern "C" void kernel_launch(void* const* d_in, const int* in_sizes, int n_in,
                              void* d_out, int out_size, void* d_ws,
                              size_t ws_size, hipStream_t stream) {
  const float* q = (const float*)d_in[0];
  const float* k = (const float*)d_in[1];
  const float* v = (const float*)d_in[2];
  const int* idx = (const int*)d_in[3];
  float* out = (float*)d_out;

  // B*S*NH = 32768 waves; 4 waves per 256-thread block -> 8192 blocks.
  const int n_blocks = (BB * SS * NHH) / 4;
  rand_attn_kernel<<<n_blocks, 256, 0, stream>>>(q, k, v, idx, out);
}